// Round 7
// baseline (726.923 us; speedup 1.0000x reference)
//
#include <hip/hip_runtime.h>
#include <float.h>

// Problem constants (match reference): B=32, N=M=128, D=256, WEIGHT=1.0
#define Bc 32
#define Nn 128
#define Dd 256

#define QSCALE 2048.0f
#define QINV   (1.0f / 2048.0f)
#define GPAD   260   // float stride per staged G row (16B-aligned, breaks 128-stride)

// ---------------------------------------------------------------------------
// DPP helpers (ctrl must be compile-time constant).
// Reduction to lane 63: ror 1/2/4/8 within 16-lane rows, then row_bcast:15/31.
// ---------------------------------------------------------------------------
template <int CTRL>
__device__ __forceinline__ float dpp_addsrc(float x) {  // old = 0
    return __int_as_float(__builtin_amdgcn_update_dpp(0, __float_as_int(x), CTRL,
                                                      0xf, 0xf, false));
}
__device__ __forceinline__ float wave_sum_lane63(float x) {
    x += dpp_addsrc<0x121>(x);
    x += dpp_addsrc<0x122>(x);
    x += dpp_addsrc<0x124>(x);
    x += dpp_addsrc<0x128>(x);
    x += dpp_addsrc<0x142>(x);
    x += dpp_addsrc<0x143>(x);
    return x;                   // lane 63 = total
}

template <int CTRL>
__device__ __forceinline__ unsigned dpp_movu(unsigned x) {  // old = UINT_MAX
    return (unsigned)__builtin_amdgcn_update_dpp((int)0xFFFFFFFFu, (int)x, CTRL,
                                                 0xf, 0xf, false);
}
// two-min over u32 keys (min, second-min) — lane 63 exact for both
template <int CTRL>
__device__ __forceinline__ void dpp2min_u32(unsigned& m1, unsigned& m2) {
    unsigned o1 = dpp_movu<CTRL>(m1);
    unsigned o2 = dpp_movu<CTRL>(m2);
    unsigned n1 = min(m1, o1);
    m2 = min(max(m1, o1), min(m2, o2));
    m1 = n1;
}

template <int CTRL>
__device__ __forceinline__ float dpp_movf(float x) {  // old = FLT_MAX
    return __int_as_float(__builtin_amdgcn_update_dpp(0x7f7fffff, __float_as_int(x),
                                                      CTRL, 0xf, 0xf, false));
}
// two-min (min, second-min counting multiplicity) over floats — for ARR
template <int CTRL>
__device__ __forceinline__ void dpp2min_step(float& m1, float& m2) {
    float o1 = dpp_movf<CTRL>(m1);
    float o2 = dpp_movf<CTRL>(m2);
    float n1 = fminf(m1, o1);
    m2 = fminf(fmaxf(m1, o1), fminf(m2, o2));
    m1 = n1;
}

__device__ __forceinline__ float readlane_f(float v, int lane) {
    return __int_as_float(__builtin_amdgcn_readlane(__float_as_int(v), lane));
}

// ---------------------------------------------------------------------------
// Fused kernel: one block per batch, 256 threads.
//   Cost phase (all 4 waves): C[i][j] = (p2[i] + g2[j] - 2*dot(p_i,g_j))/D
//     directly into LDS (same expansion as the reference einsum). G rows are
//     staged in padded LDS (GPAD=260 keeps float4 alignment, breaks the
//     128-stride bank pattern).
//   Hungarian phase (wave 0 only, barrier-free single-wave lockstep):
//     Phase 1 column reduction + greedy match; Phase 2 ARR (2 passes);
//     Phase 3 Dijkstra with packed-key two-min argmin and SPECULATIVE
//     second-min row prefetch (hides LDS latency on hits; argmin stays exact).
//   Cross-block reduce without an init dispatch: block b stores its strictly
//   positive total to ws[b] (agent release); block 0 spins until all 32 are
//   > 0 (0xAA poison = negative float, 0 = not ready) and writes out.
// ---------------------------------------------------------------------------
__global__ __launch_bounds__(256) void matcher_kernel(const float* __restrict__ P,
                                                      const float* __restrict__ G,
                                                      float* __restrict__ ws,
                                                      float* __restrict__ out) {
    const int b = blockIdx.x;
    const int tid = threadIdx.x;
    const int t = tid & 63;
    const int wv = tid >> 6;

    __shared__ float Csh[Nn * Nn];     // 64 KB
    __shared__ float gsh[64 * GPAD];   // 66.6 KB staged G half (padded)
    __shared__ float p2sh[Nn];
    __shared__ int claim[Nn];

    if (tid < Nn) {
        claim[tid] = 0x7fffffff;
        // p2[i] = sum_d P[b][i][d]^2  (one row per thread, L2-served)
        const float4* pr = (const float4*)(P + ((size_t)b * Nn + tid) * Dd);
        float s = 0.f;
        for (int d4 = 0; d4 < Dd / 4; ++d4) {
            float4 v = pr[d4];
            s += v.x * v.x + v.y * v.y + v.z * v.z + v.w * v.w;
        }
        p2sh[tid] = s;
    }

    // ---- cost phase: two halves of G ----
    const float4* G4 = (const float4*)(G + (size_t)b * Nn * Dd);
    for (int h = 0; h < 2; ++h) {
        __syncthreads();  // gsh safe to overwrite (and p2sh/claim ready at h=0)
        for (int k = 0; k < 16; ++k) {
            int e = k * 256 + tid;             // float4 index in 64x64 grid
            int row = e >> 6, c4 = e & 63;
            *(float4*)&gsh[row * GPAD + c4 * 4] = G4[(size_t)(h * 64 + row) * 64 + c4];
        }
        __syncthreads();

        const int jj = t;  // this thread's G-row within the half
        // g2 = ||g_jj||^2
        float g2 = 0.f;
        for (int d4 = 0; d4 < 64; ++d4) {
            float4 gv = *(const float4*)&gsh[jj * GPAD + d4 * 4];
            g2 += gv.x * gv.x + gv.y * gv.y + gv.z * gv.z + gv.w * gv.w;
        }
        for (int ii = wv; ii < Nn; ii += 4) {
            const float4* prow = (const float4*)(P + ((size_t)b * Nn + ii) * Dd);
            float pg = 0.f;
#pragma unroll 8
            for (int d4 = 0; d4 < 64; ++d4) {
                float4 pv = prow[d4];
                float4 gv = *(const float4*)&gsh[jj * GPAD + d4 * 4];
                pg += pv.x * gv.x + pv.y * gv.y + pv.z * gv.z + pv.w * gv.w;
            }
            Csh[ii * Nn + h * 64 + jj] =
                (p2sh[ii] + g2 - 2.0f * pg) * (1.0f / (float)Dd);
        }
    }
    __syncthreads();      // Csh complete
    if (wv != 0) return;  // waves 1-3 done; wave 0 continues barrier-free

    // ---- Phase 1: column reduction ----
    float bestA = FLT_MAX, bestB = FLT_MAX;
    int argA = 0, argB = 0;  // 0-based argmin row per owned column
    for (int i = 0; i < Nn; ++i) {
        float c0 = Csh[i * Nn + t];
        float c1 = Csh[i * Nn + t + 64];
        if (c0 < bestA) { bestA = c0; argA = i; }
        if (c1 < bestB) { bestB = c1; argB = i; }
    }
    float vA = bestA, vB = bestB;     // column potentials (reduced costs >= 0, u=0)
    atomicMin(&claim[argA], t);       // LDS atomics: in-order within the wave
    atomicMin(&claim[argB], t + 64);

    float uA = 0.0f, uB = 0.0f;       // row potentials (rows t+1, t+65)
    int pA = 0, pB = 0;               // 1-based row assigned to column (0 = free)
    if (claim[argA] == t)      pA = argA + 1;
    if (claim[argB] == t + 64) pB = argB + 1;

    unsigned long long fmA = __ballot(claim[t] == 0x7fffffff);       // free rows 1..64
    unsigned long long fmB = __ballot(claim[t + 64] == 0x7fffffff);  // free rows 65..128

    // ---- Phase 2: augmenting row reduction (2 passes, bounded, with steal) ----
    for (int pass = 0; pass < 2; ++pass) {
        if (!(fmA | fmB)) break;
        unsigned long long remA = fmA, remB = fmB;
        int guard = 0;
        while ((remA | remB) != 0ull && guard++ < 256) {
            int l, i, slotR;
            if (remA) { l = __ffsll(remA) - 1; remA &= remA - 1; i = l + 1;  slotR = 0;
                        if (!((fmA >> l) & 1)) continue; }
            else      { l = __ffsll(remB) - 1; remB &= remB - 1; i = l + 65; slotR = 1;
                        if (!((fmB >> l) & 1)) continue; }

            const float* crow = &Csh[(i - 1) * Nn];
            float cur0 = crow[t] - vA;
            float cur1 = crow[t + 64] - vB;
            float m1 = fminf(cur0, cur1);
            float m2 = fmaxf(cur0, cur1);
            dpp2min_step<0x121>(m1, m2);
            dpp2min_step<0x122>(m1, m2);
            dpp2min_step<0x124>(m1, m2);
            dpp2min_step<0x128>(m1, m2);
            dpp2min_step<0x142>(m1, m2);
            dpp2min_step<0x143>(m1, m2);
            float s_m1 = readlane_f(m1, 63);
            float s_m2 = readlane_f(m2, 63);

            unsigned long long b0 = __ballot(cur0 == s_m1);
            unsigned long long b1 = __ballot(cur1 == s_m1);
            int j1 = b0 ? __ffsll(b0) : (__ffsll(b1) + 64);  // 1-based column
            int lane1 = (j1 - 1) & 63, slot1 = (j1 - 1) >> 6;

            // u[i] = second-min (dual-feasible regardless of what follows)
            if (t == l) { if (slotR == 0) uA = s_m2; else uB = s_m2; }

            int k0 = __builtin_amdgcn_readlane(slot1 ? pB : pA, lane1);
            bool strict = (s_m1 < s_m2);
            if (!strict && k0 != 0) continue;  // tie & occupied: leave row free

            if (t == lane1) {
                if (slot1 == 0) { vA += s_m1 - s_m2; pA = i; }
                else            { vB += s_m1 - s_m2; pB = i; }
            }
            if (slotR == 0) fmA &= ~(1ull << l); else fmB &= ~(1ull << l);
            if (k0 != 0) {  // stolen row becomes free again
                int kl = (k0 - 1) & 63;
                if (k0 <= 64) { fmA |= 1ull << kl; remA |= 1ull << kl; }
                else          { fmB |= 1ull << kl; remB |= 1ull << kl; }
            }
        }
    }

    // ---- Phase 3: Dijkstra with packed two-min + speculative row prefetch ----
    for (int slotR = 0; slotR < 2; ++slotR) {
        unsigned long long mask = slotR ? fmB : fmA;
        while (mask) {
            int l = __ffsll(mask) - 1;
            mask &= mask - 1;
            int i = l + 1 + slotR * 64;  // 1-based free row

            float minvA = FLT_MAX, minvB = FLT_MAX;
            int wayA = -1, wayB = -1;    // 0-based prev col, -1 = virtual root
            bool usedA = false, usedB = false;
            bool rUA = false, rUB = false;
            if (t == l) { if (slotR == 0) rUA = true; else rUB = true; }

            int s_j0 = -1;
            float s_u = readlane_f(slotR ? uB : uA, l);  // u[i] from ARR
            int s_j1;

            float c0 = Csh[(i - 1) * Nn + t];
            float c1 = Csh[(i - 1) * Nn + t + 64];
            int s_j2prev = -1;           // speculated column from last iteration
            float sc0 = 0.f, sc1 = 0.f;  // its row's costs

            for (;;) {
                // relax free columns (clamped >= 0)
                if (!usedA) {
                    float cur = fmaxf(c0 - s_u - vA, 0.0f);
                    if (cur < minvA) { minvA = cur; wayA = s_j0; }
                }
                if (!usedB) {
                    float cur = fmaxf(c1 - s_u - vB, 0.0f);
                    if (cur < minvB) { minvB = cur; wayB = s_j0; }
                }

                // packed key: floor(minv*2048)<<16 | p<<8 | col   (exact argmin)
                unsigned kA = usedA ? 0xFFFFFFFFu
                    : ((((unsigned)(fminf(minvA, 30.0f) * QSCALE)) << 16)
                       | ((unsigned)pA << 8) | (unsigned)t);
                unsigned kB = usedB ? 0xFFFFFFFFu
                    : ((((unsigned)(fminf(minvB, 30.0f) * QSCALE)) << 16)
                       | ((unsigned)pB << 8) | (unsigned)(t + 64));
                unsigned m1 = min(kA, kB), m2 = max(kA, kB);
                dpp2min_u32<0x121>(m1, m2);
                dpp2min_u32<0x122>(m1, m2);
                dpp2min_u32<0x124>(m1, m2);
                dpp2min_u32<0x128>(m1, m2);
                dpp2min_u32<0x142>(m1, m2);
                dpp2min_u32<0x143>(m1, m2);
                unsigned key1 = (unsigned)__builtin_amdgcn_readlane((int)m1, 63);
                unsigned key2 = (unsigned)__builtin_amdgcn_readlane((int)m2, 63);

                float s_delta = (float)(key1 >> 16) * QINV;
                int s_p  = (int)((key1 >> 8) & 0xFFu);
                s_j1     = (int)(key1 & 0xFFu);
                int s_p2 = (int)((key2 >> 8) & 0xFFu);
                int s_j2 = (int)(key2 & 0xFFu);

                // next relax row: hit -> speculated regs (already resident)
                float nc0, nc1;
                if (s_j1 == s_j2prev) {
                    nc0 = sc0; nc1 = sc1;
                } else {
                    int idx = (s_p > 0 ? s_p : 1) - 1;
                    nc0 = Csh[idx * Nn + t];
                    nc1 = Csh[idx * Nn + t + 64];
                }
                // speculative load for the second-min column's row
                {
                    int idx2 = (s_p2 > 0 && s_p2 <= Nn) ? s_p2 - 1 : 0;
                    sc0 = Csh[idx2 * Nn + t];
                    sc1 = Csh[idx2 * Nn + t + 64];
                }
                s_j2prev = s_j2;

                // u[p[j1]] (pre-update value, matching reference read order)
                int pl = (s_p > 0 ? s_p : 1) - 1;
                float s_unext = readlane_f((pl >> 6) ? uB : uA, pl & 63);

                // dual updates (hide LDS latency)
                if (usedA) { vA -= s_delta; } else { minvA = fmaxf(minvA - s_delta, 0.0f); }
                if (usedB) { vB -= s_delta; } else { minvB = fmaxf(minvB - s_delta, 0.0f); }
                if (rUA) uA += s_delta;
                if (rUB) uB += s_delta;

                if (s_p == 0) break;  // augmenting path found at s_j1

                if (t == (s_j1 & 63)) { if ((s_j1 >> 6) == 0) usedA = true; else usedB = true; }
                {
                    int r = s_p - 1;
                    if (t == (r & 63)) { if ((r >> 6) == 0) rUA = true; else rUB = true; }
                }
                s_j0 = s_j1;
                s_u = s_unext;
                c0 = nc0;
                c1 = nc1;
            }

            // augment along way[] chain (uniform serial walk)
            int s_j = s_j1;
            while (s_j >= 0) {
                int lane = s_j & 63;
                int slot = s_j >> 6;
                int s_jprev = __builtin_amdgcn_readlane(slot ? wayB : wayA, lane);
                int s_pnew;
                if (s_jprev < 0) {
                    s_pnew = i;
                } else {
                    int lp = s_jprev & 63;
                    int sp = s_jprev >> 6;
                    s_pnew = __builtin_amdgcn_readlane(sp ? pB : pA, lp);
                }
                if (t == lane) {
                    if (slot == 0) pA = s_pnew; else pB = s_pnew;
                }
                s_j = s_jprev;
            }
        }
    }

    // ---- gather matched costs and publish this batch's total ----
    float tot = Csh[(pA - 1) * Nn + t] + Csh[(pB - 1) * Nn + t + 64];
    tot = wave_sum_lane63(tot);  // strictly positive (sum of 128 MSE values)

    if (t == 63) {
        __hip_atomic_store(&ws[b], tot, __ATOMIC_RELEASE, __HIP_MEMORY_SCOPE_AGENT);
    }

    // block 0 finalizes: spin until all partials are positive (poison 0xAA is a
    // tiny NEGATIVE float; zero-init is <= 0 -> both read as "not ready")
    if (b == 0) {
        float v = 0.f;
        if (t < Bc) {
            do {
                v = __hip_atomic_load(&ws[t], __ATOMIC_ACQUIRE, __HIP_MEMORY_SCOPE_AGENT);
            } while (!(v > 0.0f));
        }
        float x = (t < Bc) ? v : 0.0f;
        x = wave_sum_lane63(x);
        if (t == 63) out[0] = x * (1.0f / ((float)Nn * (float)Bc));
    }
}

extern "C" void kernel_launch(void* const* d_in, const int* in_sizes, int n_in,
                              void* d_out, int out_size, void* d_ws, size_t ws_size,
                              hipStream_t stream) {
    const float* P = (const float*)d_in[0];   // batch_prediction  [32,128,256] f32
    const float* G = (const float*)d_in[1];   // batch_groundtruth [32,128,256] f32
    float* out = (float*)d_out;               // [1] f32
    float* ws = (float*)d_ws;                 // ws[0..31]: per-batch totals

    matcher_kernel<<<Bc, 256, 0, stream>>>(P, G, ws, out);
}

// Round 8
// 581.852 us; speedup vs baseline: 1.2493x; 1.2493x over previous
//
#include <hip/hip_runtime.h>
#include <hip/hip_fp16.h>
#include <float.h>

// Problem constants (match reference): B=32, N=M=128, D=256, WEIGHT=1.0
#define Bc 32
#define Nn 128
#define Dd 256

#define QSCALE 2048.0f
#define QINV   (1.0f / 2048.0f)
#define GPAD   260   // float stride per staged G row (16B-aligned, breaks 128-stride)

// ---------------------------------------------------------------------------
// DPP helpers (ctrl must be compile-time constant).
// Reduction to lane 63: ror 1/2/4/8 within 16-lane rows, then row_bcast:15/31.
// ---------------------------------------------------------------------------
template <int CTRL>
__device__ __forceinline__ float dpp_addsrc(float x) {  // old = 0
    return __int_as_float(__builtin_amdgcn_update_dpp(0, __float_as_int(x), CTRL,
                                                      0xf, 0xf, false));
}
__device__ __forceinline__ float wave_sum_lane63(float x) {
    x += dpp_addsrc<0x121>(x);
    x += dpp_addsrc<0x122>(x);
    x += dpp_addsrc<0x124>(x);
    x += dpp_addsrc<0x128>(x);
    x += dpp_addsrc<0x142>(x);
    x += dpp_addsrc<0x143>(x);
    return x;                   // lane 63 = total
}

template <int CTRL>
__device__ __forceinline__ unsigned dpp_movu(unsigned x) {  // old = UINT_MAX
    return (unsigned)__builtin_amdgcn_update_dpp((int)0xFFFFFFFFu, (int)x, CTRL,
                                                 0xf, 0xf, false);
}
__device__ __forceinline__ unsigned wave_umin_lane63(unsigned x) {
    x = min(x, dpp_movu<0x121>(x));
    x = min(x, dpp_movu<0x122>(x));
    x = min(x, dpp_movu<0x124>(x));
    x = min(x, dpp_movu<0x128>(x));
    x = min(x, dpp_movu<0x142>(x));
    x = min(x, dpp_movu<0x143>(x));
    return x;                   // lane 63 = min of all 64 lanes
}

template <int CTRL>
__device__ __forceinline__ float dpp_movf(float x) {  // old = FLT_MAX
    return __int_as_float(__builtin_amdgcn_update_dpp(0x7f7fffff, __float_as_int(x),
                                                      CTRL, 0xf, 0xf, false));
}
// two-min (min, second-min counting multiplicity) over floats — ARR only
template <int CTRL>
__device__ __forceinline__ void dpp2min_step(float& m1, float& m2) {
    float o1 = dpp_movf<CTRL>(m1);
    float o2 = dpp_movf<CTRL>(m2);
    float n1 = fminf(m1, o1);
    m2 = fminf(fmaxf(m1, o1), fminf(m2, o2));
    m1 = n1;
}

__device__ __forceinline__ float readlane_f(float v, int lane) {
    return __int_as_float(__builtin_amdgcn_readlane(__float_as_int(v), lane));
}

// ---------------------------------------------------------------------------
// Fused kernel: one block per batch, 256 threads.
//   Cost phase (all 4 waves): C[i][j] = (p2[i]+g2[j]-2*dot)/D into f32 LDS,
//     G staged in padded LDS. Then all threads pack a half2 selection copy
//     H[row*64+t] = (C[row][t], C[row][t+64]) into the (dead) gsh space:
//     ONE ds_read_b32 per lane per Dijkstra step, bank-conflict-free.
//   Hungarian phase (wave 0 only, barrier-free lockstep):
//     Phase 1 column reduction + greedy match; Phase 2 ARR (3 passes);
//     Phase 3 Dijkstra, single-min packed key [minv*2048 |15:8 p |7:0 col]
//     (round-6 structure — two-min + speculation regressed in round 7).
//   fp16 only perturbs SELECTION; the final gather sums f32 costs, so loss
//   error = assignment suboptimality <= 2*N*2^-11*|C| ~1e-3 << 3.4e-2.
//   Cross-block reduce: block b stores its strictly positive total to ws[b]
//   (agent release); block 0 spins until all 32 are > 0 (0xAA poison reads
//   as a tiny negative float) and writes out.
// ---------------------------------------------------------------------------
__global__ __launch_bounds__(256) void matcher_kernel(const float* __restrict__ P,
                                                      const float* __restrict__ G,
                                                      float* __restrict__ ws,
                                                      float* __restrict__ out) {
    const int b = blockIdx.x;
    const int tid = threadIdx.x;
    const int t = tid & 63;
    const int wv = tid >> 6;

    __shared__ float Csh[Nn * Nn];     // 64 KB f32 costs (exact gather)
    __shared__ float gsh[64 * GPAD];   // 66.6 KB: G staging, then half2 H copy
    __shared__ float p2sh[Nn];
    __shared__ int claim[Nn];
    __half2* H = (__half2*)gsh;        // H[row*64+t] = (C[row][t], C[row][t+64])

    if (tid < Nn) {
        claim[tid] = 0x7fffffff;
        const float4* pr = (const float4*)(P + ((size_t)b * Nn + tid) * Dd);
        float s = 0.f;
        for (int d4 = 0; d4 < Dd / 4; ++d4) {
            float4 v = pr[d4];
            s += v.x * v.x + v.y * v.y + v.z * v.z + v.w * v.w;
        }
        p2sh[tid] = s;
    }

    // ---- cost phase: two halves of G ----
    const float4* G4 = (const float4*)(G + (size_t)b * Nn * Dd);
    for (int h = 0; h < 2; ++h) {
        __syncthreads();  // gsh safe to overwrite (and p2sh/claim ready at h=0)
        for (int k = 0; k < 16; ++k) {
            int e = k * 256 + tid;             // float4 index in 64x64 grid
            int row = e >> 6, c4 = e & 63;
            *(float4*)&gsh[row * GPAD + c4 * 4] = G4[(size_t)(h * 64 + row) * 64 + c4];
        }
        __syncthreads();

        const int jj = t;  // this thread's G-row within the half
        float g2 = 0.f;
        for (int d4 = 0; d4 < 64; ++d4) {
            float4 gv = *(const float4*)&gsh[jj * GPAD + d4 * 4];
            g2 += gv.x * gv.x + gv.y * gv.y + gv.z * gv.z + gv.w * gv.w;
        }
        for (int ii = wv; ii < Nn; ii += 4) {
            const float4* prow = (const float4*)(P + ((size_t)b * Nn + ii) * Dd);
            float pg = 0.f;
#pragma unroll 8
            for (int d4 = 0; d4 < 64; ++d4) {
                float4 pv = prow[d4];
                float4 gv = *(const float4*)&gsh[jj * GPAD + d4 * 4];
                pg += pv.x * gv.x + pv.y * gv.y + pv.z * gv.z + pv.w * gv.w;
            }
            Csh[ii * Nn + h * 64 + jj] =
                (p2sh[ii] + g2 - 2.0f * pg) * (1.0f / (float)Dd);
        }
    }
    __syncthreads();      // Csh complete; gsh dead

    // ---- pack half2 selection copy (all 256 threads) ----
    for (int e = tid; e < Nn * 64; e += 256) {
        int row = e >> 6, c = e & 63;
        H[e] = __halves2half2(__float2half_rn(Csh[row * Nn + c]),
                              __float2half_rn(Csh[row * Nn + c + 64]));
    }
    __syncthreads();
    if (wv != 0) return;  // waves 1-3 done; wave 0 continues barrier-free

    // ---- Phase 1: column reduction (from H) ----
    float bestA = FLT_MAX, bestB = FLT_MAX;
    int argA = 0, argB = 0;  // 0-based argmin row per owned column
    for (int i = 0; i < Nn; ++i) {
        __half2 hc = H[i * 64 + t];
        float c0 = __low2float(hc);
        float c1 = __high2float(hc);
        if (c0 < bestA) { bestA = c0; argA = i; }
        if (c1 < bestB) { bestB = c1; argB = i; }
    }
    float vA = bestA, vB = bestB;     // column potentials (reduced costs >= 0, u=0)
    atomicMin(&claim[argA], t);       // LDS atomics: in-order within the wave
    atomicMin(&claim[argB], t + 64);

    float uA = 0.0f, uB = 0.0f;       // row potentials (rows t+1, t+65)
    int pA = 0, pB = 0;               // 1-based row assigned to column (0 = free)
    if (claim[argA] == t)      pA = argA + 1;
    if (claim[argB] == t + 64) pB = argB + 1;

    unsigned long long fmA = __ballot(claim[t] == 0x7fffffff);       // free rows 1..64
    unsigned long long fmB = __ballot(claim[t + 64] == 0x7fffffff);  // free rows 65..128

    // ---- Phase 2: augmenting row reduction (3 passes, bounded, with steal) ----
    for (int pass = 0; pass < 3; ++pass) {
        if (!(fmA | fmB)) break;
        unsigned long long remA = fmA, remB = fmB;
        int guard = 0;
        while ((remA | remB) != 0ull && guard++ < 256) {
            int l, i, slotR;
            if (remA) { l = __ffsll(remA) - 1; remA &= remA - 1; i = l + 1;  slotR = 0;
                        if (!((fmA >> l) & 1)) continue; }
            else      { l = __ffsll(remB) - 1; remB &= remB - 1; i = l + 65; slotR = 1;
                        if (!((fmB >> l) & 1)) continue; }

            __half2 hr = H[(i - 1) * 64 + t];
            float cur0 = __low2float(hr) - vA;
            float cur1 = __high2float(hr) - vB;
            float m1 = fminf(cur0, cur1);
            float m2 = fmaxf(cur0, cur1);
            dpp2min_step<0x121>(m1, m2);
            dpp2min_step<0x122>(m1, m2);
            dpp2min_step<0x124>(m1, m2);
            dpp2min_step<0x128>(m1, m2);
            dpp2min_step<0x142>(m1, m2);
            dpp2min_step<0x143>(m1, m2);
            float s_m1 = readlane_f(m1, 63);
            float s_m2 = readlane_f(m2, 63);

            unsigned long long b0 = __ballot(cur0 == s_m1);
            unsigned long long b1 = __ballot(cur1 == s_m1);
            int j1 = b0 ? __ffsll(b0) : (__ffsll(b1) + 64);  // 1-based column
            int lane1 = (j1 - 1) & 63, slot1 = (j1 - 1) >> 6;

            // u[i] = second-min (dual-feasible regardless of what follows)
            if (t == l) { if (slotR == 0) uA = s_m2; else uB = s_m2; }

            int k0 = __builtin_amdgcn_readlane(slot1 ? pB : pA, lane1);
            bool strict = (s_m1 < s_m2);
            if (!strict && k0 != 0) continue;  // tie & occupied: leave row free

            if (t == lane1) {
                if (slot1 == 0) { vA += s_m1 - s_m2; pA = i; }
                else            { vB += s_m1 - s_m2; pB = i; }
            }
            if (slotR == 0) fmA &= ~(1ull << l); else fmB &= ~(1ull << l);
            if (k0 != 0) {  // stolen row becomes free again
                int kl = (k0 - 1) & 63;
                if (k0 <= 64) { fmA |= 1ull << kl; remA |= 1ull << kl; }
                else          { fmB |= 1ull << kl; remB |= 1ull << kl; }
            }
        }
    }

    // ---- Phase 3: Dijkstra, single-min packed key (round-6 structure) ----
    for (int slotR = 0; slotR < 2; ++slotR) {
        unsigned long long mask = slotR ? fmB : fmA;
        while (mask) {
            int l = __ffsll(mask) - 1;
            mask &= mask - 1;
            int i = l + 1 + slotR * 64;  // 1-based free row

            float minvA = FLT_MAX, minvB = FLT_MAX;
            int wayA = -1, wayB = -1;    // 0-based prev col, -1 = virtual root
            bool usedA = false, usedB = false;
            bool rUA = false, rUB = false;
            if (t == l) { if (slotR == 0) rUA = true; else rUB = true; }

            int s_j0 = -1;
            float s_u = readlane_f(slotR ? uB : uA, l);  // u[i] from ARR
            int s_j1;

            __half2 hc = H[(i - 1) * 64 + t];  // row i costs (this lane's 2 cols)

            for (;;) {
                float c0 = __low2float(hc);
                float c1 = __high2float(hc);
                // relax free columns (clamped >= 0)
                if (!usedA) {
                    float cur = fmaxf(c0 - s_u - vA, 0.0f);
                    if (cur < minvA) { minvA = cur; wayA = s_j0; }
                }
                if (!usedB) {
                    float cur = fmaxf(c1 - s_u - vB, 0.0f);
                    if (cur < minvB) { minvB = cur; wayB = s_j0; }
                }

                // packed key: floor(minv*2048)<<16 | p<<8 | col   (exact argmin)
                unsigned kA = usedA ? 0xFFFFFFFFu
                    : ((((unsigned)(fminf(minvA, 30.0f) * QSCALE)) << 16)
                       | ((unsigned)pA << 8) | (unsigned)t);
                unsigned kB = usedB ? 0xFFFFFFFFu
                    : ((((unsigned)(fminf(minvB, 30.0f) * QSCALE)) << 16)
                       | ((unsigned)pB << 8) | (unsigned)(t + 64));
                unsigned k = wave_umin_lane63(min(kA, kB));
                unsigned s_key = (unsigned)__builtin_amdgcn_readlane((int)k, 63);
                float s_delta = (float)(s_key >> 16) * QINV;
                int s_p = (int)((s_key >> 8) & 0xFFu);  // row assigned to argmin col
                s_j1 = (int)(s_key & 0xFFu);            // 0-based argmin column

                // prefetch next cost row + u[s_p] (issue before dual updates)
                int idx = (s_p > 0 ? s_p : 1) - 1;
                __half2 nhc = H[idx * 64 + t];
                float s_unext = readlane_f((idx >> 6) ? uB : uA, idx & 63);

                // dual updates (hide the LDS latency)
                if (usedA) { vA -= s_delta; } else { minvA = fmaxf(minvA - s_delta, 0.0f); }
                if (usedB) { vB -= s_delta; } else { minvB = fmaxf(minvB - s_delta, 0.0f); }
                if (rUA) uA += s_delta;
                if (rUB) uB += s_delta;

                if (s_p == 0) break;  // augmenting path found at s_j1

                if (t == (s_j1 & 63)) { if ((s_j1 >> 6) == 0) usedA = true; else usedB = true; }
                {
                    int r = s_p - 1;
                    if (t == (r & 63)) { if ((r >> 6) == 0) rUA = true; else rUB = true; }
                }
                s_j0 = s_j1;
                s_u = s_unext;
                hc = nhc;
            }

            // augment along way[] chain (uniform serial walk)
            int s_j = s_j1;
            while (s_j >= 0) {
                int lane = s_j & 63;
                int slot = s_j >> 6;
                int s_jprev = __builtin_amdgcn_readlane(slot ? wayB : wayA, lane);
                int s_pnew;
                if (s_jprev < 0) {
                    s_pnew = i;
                } else {
                    int lp = s_jprev & 63;
                    int sp = s_jprev >> 6;
                    s_pnew = __builtin_amdgcn_readlane(sp ? pB : pA, lp);
                }
                if (t == lane) {
                    if (slot == 0) pA = s_pnew; else pB = s_pnew;
                }
                s_j = s_jprev;
            }
        }
    }

    // ---- gather matched costs from EXACT f32 Csh and publish ----
    float tot = Csh[(pA - 1) * Nn + t] + Csh[(pB - 1) * Nn + t + 64];
    tot = wave_sum_lane63(tot);  // strictly positive (sum of 128 MSE values)

    if (t == 63) {
        __hip_atomic_store(&ws[b], tot, __ATOMIC_RELEASE, __HIP_MEMORY_SCOPE_AGENT);
    }

    // block 0 finalizes: spin until all partials are positive (poison 0xAA is a
    // tiny NEGATIVE float; zero-init is <= 0 -> both read as "not ready")
    if (b == 0) {
        float v = 0.f;
        if (t < Bc) {
            do {
                v = __hip_atomic_load(&ws[t], __ATOMIC_ACQUIRE, __HIP_MEMORY_SCOPE_AGENT);
            } while (!(v > 0.0f));
        }
        float x = (t < Bc) ? v : 0.0f;
        x = wave_sum_lane63(x);
        if (t == 63) out[0] = x * (1.0f / ((float)Nn * (float)Bc));
    }
}

extern "C" void kernel_launch(void* const* d_in, const int* in_sizes, int n_in,
                              void* d_out, int out_size, void* d_ws, size_t ws_size,
                              hipStream_t stream) {
    const float* P = (const float*)d_in[0];   // batch_prediction  [32,128,256] f32
    const float* G = (const float*)d_in[1];   // batch_groundtruth [32,128,256] f32
    float* out = (float*)d_out;               // [1] f32
    float* ws = (float*)d_ws;                 // ws[0..31]: per-batch totals

    matcher_kernel<<<Bc, 256, 0, stream>>>(P, G, ws, out);
}